// Round 18
// baseline (166.796 us; speedup 1.0000x reference)
//
#include <hip/hip_runtime.h>
#include <stdint.h>

// ImportanceGuidedCrossAttention: B=2, N=1024, M=4096, HEADS=16, DHEAD=64
// prep; tcvt4; gemm_qkv (Q + K + V^T in ONE 288-block launch, 256^2 tiles /
// 8 waves [R12-verified structure] + slot-XOR LDS swizzle [R16/17-verified,
// 0 conflicts] + V decode m-fastest [R16/17-verified]; dbuf drain fence);
// fused attention (LDS K/V, permuted-K lane-local P, ones-MFMA lsum, split-K);
// combine; O proj (128^2, R17-verified).

typedef float f32x4 __attribute__((ext_vector_type(4)));
typedef __bf16 bf16x8 __attribute__((ext_vector_type(8)));

#define SCALE 0.125f
#define LOG2E 1.4426950408889634f
#define N_Q 1024
#define M_KV 4096
#define KDIM 1024

static __device__ __forceinline__ unsigned short f2bf(float f) {
  union { float f; unsigned int u; } v; v.f = f;
  unsigned int r = v.u + 0x7fffu + ((v.u >> 16) & 1u);  // RNE
  return (unsigned short)(r >> 16);
}
static __device__ __forceinline__ unsigned int cvtpk(float lo, float hi) {
  unsigned int r;
  asm("v_cvt_pk_bf16_f32 %0, %1, %2" : "=v"(r) : "v"(lo), "v"(hi));
  return r;
}
static __device__ __forceinline__ float exp2a(float x) {
  float r;
  asm("v_exp_f32 %0, %1" : "=v"(r) : "v"(x));
  return r;
}
static __device__ __forceinline__ void gload16(const void* g, void* l) {
  __builtin_amdgcn_global_load_lds(
      (const __attribute__((address_space(1))) void*)g,
      (__attribute__((address_space(3))) void*)l, 16, 0, 0);
}
static __device__ __forceinline__ void gload4(const void* g, void* l) {
  __builtin_amdgcn_global_load_lds(
      (const __attribute__((address_space(1))) void*)g,
      (__attribute__((address_space(3))) void*)l, 4, 0, 0);
}
// drain fence (rule #18: sched_barrier pins reordering across the raw barrier)
static __device__ __forceinline__ void fence0() {
  asm volatile("s_waitcnt vmcnt(0)" ::: "memory");
  __builtin_amdgcn_s_barrier();
  __builtin_amdgcn_sched_barrier(0);
}

// ---------------- prep: cvt x, cvt ctx, scale imp — one launch ----------------
__global__ __launch_bounds__(256) void prep(const float* __restrict__ x,
                                            const float* __restrict__ ctx,
                                            const float* __restrict__ imp,
                                            unsigned short* __restrict__ xb,
                                            unsigned short* __restrict__ cb,
                                            float* __restrict__ impL) {
  const int NX = (2048 * 1024) / 4;
  const int NC = (8192 * 1024) / 4;
  const int NI = 8192 / 4;
  int i = blockIdx.x * 256 + threadIdx.x;
  int stride = gridDim.x * 256;
  for (; i < NX + NC + NI; i += stride) {
    if (i < NX) {
      float4 v = reinterpret_cast<const float4*>(x)[i];
      ushort4 o; o.x = f2bf(v.x); o.y = f2bf(v.y); o.z = f2bf(v.z); o.w = f2bf(v.w);
      reinterpret_cast<ushort4*>(xb)[i] = o;
    } else if (i < NX + NC) {
      int j = i - NX;
      float4 v = reinterpret_cast<const float4*>(ctx)[j];
      ushort4 o; o.x = f2bf(v.x); o.y = f2bf(v.y); o.z = f2bf(v.z); o.w = f2bf(v.w);
      reinterpret_cast<ushort4*>(cb)[j] = o;
    } else {
      int j = i - NX - NC;
      float4 v = reinterpret_cast<const float4*>(imp)[j];
      float4 o; o.x = v.x * LOG2E; o.y = v.y * LOG2E; o.z = v.z * LOG2E; o.w = v.w * LOG2E;
      reinterpret_cast<float4*>(impL)[j] = o;
    }
  }
}

// ---------------- fp32 [R][C] -> bf16 [C][R] transpose-convert, 4 weights ----------------
__global__ __launch_bounds__(256) void tcvt4(const float* __restrict__ w0,
                                             const float* __restrict__ w1,
                                             const float* __restrict__ w2,
                                             const float* __restrict__ w3,
                                             unsigned short* __restrict__ o0,
                                             unsigned short* __restrict__ o1,
                                             unsigned short* __restrict__ o2,
                                             unsigned short* __restrict__ o3) {
  const int R = 1024, C = 1024;
  __shared__ float tile[32][33];
  const float* in; unsigned short* out;
  switch (blockIdx.z) {
    case 0: in = w0; out = o0; break;
    case 1: in = w1; out = o1; break;
    case 2: in = w2; out = o2; break;
    default: in = w3; out = o3; break;
  }
  int bx = blockIdx.x * 32, by = blockIdx.y * 32;
  int x = threadIdx.x & 31;
  int y0 = threadIdx.x >> 5;
  #pragma unroll
  for (int yy = y0; yy < 32; yy += 8)
    tile[yy][x] = in[(size_t)(by + yy) * C + bx + x];
  __syncthreads();
  #pragma unroll
  for (int yy = y0; yy < 32; yy += 8)
    out[(size_t)(bx + yy) * R + by + x] = f2bf(tile[x][yy]);
}

// ---------------- mega projection GEMM: Q + K + V^T, 256^2 tiles, 8 waves ----------------
// 288 blocks (bijective XCD swizzle); 64KB LDS -> doubled-up CUs co-reside:
//  swz <32   : Q  = xb[2048x1024] @ Wqt^T  -> qa   (8m x 4n, n-fastest)
//  swz <160  : K  = cb[8192x1024] @ Wkt^T  -> ka   (32m x 4n, n-fastest: A=cb panel reuse)
//  else      : Vt = Wvt[1024x1024] @ cb^T  -> vtb  (4m x 32n, m-fastest: B=cb panel reuse)
// BK=32, 8 waves (2m x 4n, wave owns 128x64 -> 32 MFMA per fence = 2x the
// 128^2 ratio). Dbuf + drain fence after compute. Slot-XOR swizzle
// s(row)=(row>>1)&3 store-side via pre-swizzled source (rule #21).
__global__ __launch_bounds__(512) void gemm_qkv(const unsigned short* __restrict__ xb,
                                                const unsigned short* __restrict__ cb,
                                                const unsigned short* __restrict__ Wqt,
                                                const unsigned short* __restrict__ Wkt,
                                                const unsigned short* __restrict__ Wvt,
                                                unsigned short* __restrict__ qa,
                                                unsigned short* __restrict__ ka,
                                                unsigned short* __restrict__ vtb) {
  const int LDT = 32;
  __shared__ __align__(16) unsigned short As[2][256 * LDT];
  __shared__ __align__(16) unsigned short Bs[2][256 * LDT];

  const int nwg = gridDim.x;                     // 288, %8==0
  const int lin = blockIdx.x;
  const int swz = (lin & 7) * (nwg >> 3) + (lin >> 3);

  int variant, m0, n0;
  if (swz < 32)       { variant = 0; m0 = (swz >> 2) * 256;        n0 = (swz & 3) * 256; }
  else if (swz < 160) { int r = swz - 32;  variant = 1; m0 = (r >> 2) * 256; n0 = (r & 3) * 256; }
  else                { int r = swz - 160; variant = 2; m0 = (r & 3) * 256;  n0 = (r >> 2) * 256; }
  const unsigned short* A  = (variant == 0) ? xb  : (variant == 1) ? cb  : Wvt;
  const unsigned short* Bt = (variant == 0) ? Wqt : (variant == 1) ? Wkt : cb;

  const int t = threadIdx.x;
  const int wave = t >> 6, lane = t & 63;
  const int wr = wave >> 2, wc = wave & 3;       // 2m x 4n waves -> 128x64 per wave
  const int lrow = lane & 15, g = lane >> 4;

  f32x4 acc[8][4] = {};

  const int r16 = lane >> 2;                               // staging row in 16-row chunk
  const int cs8 = (((lane & 3) ^ ((r16 >> 1) & 3)) * 8);   // pre-swizzled src col (elems)
  const int rb = wave * 32;                                // wave's 32-row chunk of 256
  const int gsw = (g ^ ((lrow >> 1) & 3)) * 8;             // swizzled read col (elems)

  auto STAGE = [&](int bi, int k0) {
    gload16(&A[(size_t)(m0 + rb + r16) * KDIM + k0 + cs8],       &As[bi][rb * LDT]);
    gload16(&A[(size_t)(m0 + rb + 16 + r16) * KDIM + k0 + cs8],  &As[bi][(rb + 16) * LDT]);
    gload16(&Bt[(size_t)(n0 + rb + r16) * KDIM + k0 + cs8],      &Bs[bi][rb * LDT]);
    gload16(&Bt[(size_t)(n0 + rb + 16 + r16) * KDIM + k0 + cs8], &Bs[bi][(rb + 16) * LDT]);
  };
  auto COMPUTE = [&](int buf) {
    bf16x8 af[8], bfr[4];
    #pragma unroll
    for (int mi = 0; mi < 8; mi++)
      af[mi] = *reinterpret_cast<const bf16x8*>(&As[buf][(wr * 128 + mi * 16 + lrow) * LDT + gsw]);
    #pragma unroll
    for (int ni = 0; ni < 4; ni++)
      bfr[ni] = *reinterpret_cast<const bf16x8*>(&Bs[buf][(wc * 64 + ni * 16 + lrow) * LDT + gsw]);
    #pragma unroll
    for (int mi = 0; mi < 8; mi++)
      #pragma unroll
      for (int ni = 0; ni < 4; ni++)
        acc[mi][ni] = __builtin_amdgcn_mfma_f32_16x16x32_bf16(af[mi], bfr[ni], acc[mi][ni], 0, 0, 0);
  };

  STAGE(0, 0);
  fence0();

  for (int k0 = 0; k0 < KDIM; k0 += 32) {
    const int buf = (k0 >> 5) & 1;
    if (k0 + 32 < KDIM) STAGE(buf ^ 1, k0 + 32);   // issue next stage before compute
    COMPUTE(buf);
    fence0();                                       // drain (covered by compute + co-resident block)
  }

  // epilogue: C/D layout col=lane&15, row=g*4+reg — all variants coalesced (R12-verified)
  #pragma unroll
  for (int mi = 0; mi < 8; mi++) {
    #pragma unroll
    for (int ni = 0; ni < 4; ni++) {
      #pragma unroll
      for (int r = 0; r < 4; r++) {
        int R = m0 + wr * 128 + mi * 16 + g * 4 + r;
        int Cc = n0 + wc * 64 + ni * 16 + lrow;
        unsigned short bv = f2bf(acc[mi][ni][r]);
        if (variant == 0) {
          int h = Cc >> 6, d = Cc & 63;
          int b = R >> 10, n = R & 1023;
          qa[(((size_t)(b * 16 + h)) * 1024 + n) * 64 + d] = bv;
        } else if (variant == 1) {
          int h = Cc >> 6, d = Cc & 63;
          int b = R >> 12, m = R & 4095;
          ka[(((size_t)(b * 16 + h)) * 4096 + m) * 64 + d] = bv;
        } else {
          int h = R >> 6, d = R & 63;        // rows are the inner (h,d) index
          int b = Cc >> 12, m = Cc & 4095;   // cols are (b,m) -> contiguous m per lane
          vtb[(((size_t)(b * 16 + h)) * 64 + d) * 4096 + m] = bv;
        }
      }
    }
  }
}

// ---------------- O-proj GEMM: out[2048][1024] = ao @ Wot^T + bo (f32) ----------------
// 1D grid of 128 blocks; dbuf drain pipeline + swizzle (R17-verified).
__global__ __launch_bounds__(256) void gemm_o(const unsigned short* __restrict__ A,
                                              const unsigned short* __restrict__ Bt,
                                              float* __restrict__ outp,
                                              const float* __restrict__ bias) {
  const int LDT = 32;
  __shared__ __align__(16) unsigned short As[2][128 * LDT];
  __shared__ __align__(16) unsigned short Bs[2][128 * LDT];

  const int nwg = gridDim.x;                     // 128
  const int lin = blockIdx.x;
  const int swz = (lin & 7) * (nwg >> 3) + (lin >> 3);
  const int m0 = (swz >> 3) * 128;
  const int n0 = (swz & 7) * 128;

  const int t = threadIdx.x;
  const int wave = t >> 6, lane = t & 63;
  const int wr = wave >> 1, wc = wave & 1;
  const int lrow = lane & 15, g = lane >> 4;

  f32x4 acc[4][4] = {};

  const int r16 = lane >> 2;
  const int cs8 = (((lane & 3) ^ ((r16 >> 1) & 3)) * 8);
  const int rb = wave * 32;
  const int gsw = (g ^ ((lrow >> 1) & 3)) * 8;

  auto STAGE = [&](int bi, int k0) {
    gload16(&A[(size_t)(m0 + rb + r16) * KDIM + k0 + cs8],       &As[bi][rb * LDT]);
    gload16(&A[(size_t)(m0 + rb + 16 + r16) * KDIM + k0 + cs8],  &As[bi][(rb + 16) * LDT]);
    gload16(&Bt[(size_t)(n0 + rb + r16) * KDIM + k0 + cs8],      &Bs[bi][rb * LDT]);
    gload16(&Bt[(size_t)(n0 + rb + 16 + r16) * KDIM + k0 + cs8], &Bs[bi][(rb + 16) * LDT]);
  };
  auto COMPUTE = [&](int buf) {
    bf16x8 af[4], bfr[4];
    #pragma unroll
    for (int mi = 0; mi < 4; mi++)
      af[mi] = *reinterpret_cast<const bf16x8*>(&As[buf][(wr * 64 + mi * 16 + lrow) * LDT + gsw]);
    #pragma unroll
    for (int ni = 0; ni < 4; ni++)
      bfr[ni] = *reinterpret_cast<const bf16x8*>(&Bs[buf][(wc * 64 + ni * 16 + lrow) * LDT + gsw]);
    #pragma unroll
    for (int mi = 0; mi < 4; mi++)
      #pragma unroll
      for (int ni = 0; ni < 4; ni++)
        acc[mi][ni] = __builtin_amdgcn_mfma_f32_16x16x32_bf16(af[mi], bfr[ni], acc[mi][ni], 0, 0, 0);
  };

  STAGE(0, 0);
  fence0();

  for (int k0 = 0; k0 < KDIM; k0 += 32) {
    const int buf = (k0 >> 5) & 1;
    if (k0 + 32 < KDIM) STAGE(buf ^ 1, k0 + 32);
    COMPUTE(buf);
    fence0();
  }

  #pragma unroll
  for (int mi = 0; mi < 4; mi++)
    #pragma unroll
    for (int ni = 0; ni < 4; ni++)
      #pragma unroll
      for (int r = 0; r < 4; r++) {
        int R = m0 + wr * 64 + mi * 16 + g * 4 + r;
        int Cc = n0 + wc * 64 + ni * 16 + lrow;
        outp[(size_t)R * 1024 + Cc] = acc[mi][ni][r] + bias[Cc];
      }
}

// ---------------- fused attention: LDS K/V + permuted-K lane-local P ----------------
// Verified math (R8/R11); ONE raw barrier/iter with vmcnt(0) AFTER compute.
__global__ __launch_bounds__(256, 4) void attn_kernel(const unsigned short* __restrict__ q,
                                                      const unsigned short* __restrict__ k,
                                                      const unsigned short* __restrict__ vt,
                                                      const float* __restrict__ impL,
                                                      float* __restrict__ acc_ws,
                                                      float* __restrict__ l_ws,
                                                      int split, int lsplit) {
  __shared__ __align__(16) unsigned short Ks[2][64 * 64];
  __shared__ __align__(16) unsigned short Vs[2][64 * 64];
  __shared__ __align__(16) float Bls[2][64];

  const int nwg = gridDim.x;                    // 256*split, %8==0
  const int lin = blockIdx.x;
  const int swz = (lin & 7) * (nwg >> 3) + (lin >> 3);
  const int sp = swz & (split - 1);
  const int tmp = swz >> lsplit;
  const int qt8 = tmp & 7;
  const int bh = tmp >> 3;                      // b*16+h
  const int t = threadIdx.x;
  const int wave = t >> 6, lane = t & 63;
  const int lrow = lane & 15, g = lane >> 4;
  const int q0 = qt8 * 128 + wave * 32;

  const unsigned short* qbase = q + ((size_t)bh * N_Q + q0) * 64;
  const char* kbase = (const char*)(k + (size_t)bh * M_KV * 64);
  const char* vbase = (const char*)(vt + (size_t)bh * 64 * M_KV);
  const float* ibase = impL + (size_t)(bh >> 4) * M_KV;

  const int rj = lane >> 3;
  const int cb = (lane & 7) * 16;
  const int cbsV  = cb ^ (rj << 4);
  const int cbsK0 = cb ^ ((rj & 3) << 4);
  const int cbsK1 = cb ^ (((rj & 3) | 4) << 4);
  const int row0 = wave * 16 + rj;
  const int row1 = row0 + 8;

  const int g2 = lrow >> 2, r4 = lrow & 3;
  const int krA = g2 * 8 + r4;
  const int vk = r4 | ((g2 & 1) << 2);
  const int offK0 = (g * 16) ^ (vk << 4);
  const int offK1 = (g * 16 + 64) ^ (vk << 4);
  const int swrV = (lrow & 7) << 4;
  const int offV0 = (g * 16) ^ swrV;
  const int offV1 = (g * 16 + 64) ^ swrV;

  bf16x8 qf[2][2];
  #pragma unroll
  for (int s = 0; s < 2; s++)
    #pragma unroll
    for (int ks = 0; ks < 2; ks++)
      qf[s][ks] = *reinterpret_cast<const bf16x8*>(&qbase[(size_t)(s * 16 + lrow) * 64 + ks * 32 + g * 8]);

  f32x4 acc[2][4] = {};
  f32x4 accL[2] = {};

  union { unsigned int u[4]; bf16x8 v; } onesU;
  onesU.u[0] = 0x3F803F80u; onesU.u[1] = 0x3F803F80u;
  onesU.u[2] = 0x3F803F80u; onesU.u[3] = 0x3F803F80u;

  const float S2 = SCALE * LOG2E;
  const int mspan = M_KV >> lsplit;
  const int mlo = sp * mspan;
  const int nt = mspan >> 6;

  auto STAGE = [&](int bi, int m0) {
    gload16(kbase + (size_t)(m0 + row0) * 128 + cbsK0, &Ks[bi][(wave * 16) * 64]);
    gload16(kbase + (size_t)(m0 + row1) * 128 + cbsK1, &Ks[bi][(wave * 16 + 8) * 64]);
    gload16(vbase + (size_t)row0 * 8192 + (size_t)m0 * 2 + cbsV, &Vs[bi][(wave * 16) * 64]);
    gload16(vbase + (size_t)row1 * 8192 + (size_t)m0 * 2 + cbsV, &Vs[bi][(wave * 16 + 8) * 64]);
    gload4((const char*)(ibase + m0) + lane * 4, &Bls[bi][0]);
  };

  STAGE(0, mlo);
  fence0();

  for (int tt = 0; tt < nt; ++tt) {
    const int cur = tt & 1;
    if (tt + 1 < nt) STAGE(cur ^ 1, mlo + (tt + 1) * 64);   // async; waited at iter end

    const char* K_ = (const char*)&Ks[cur][0];
    const char* V_ = (const char*)&Vs[cur][0];
    const float* B_ = &Bls[cur][0];

    bf16x8 pfr[2][2];
    #pragma unroll
    for (int h = 0; h < 2; h++) {
      const char* kp = K_ + (size_t)(h * 32 + krA) * 128;
      bf16x8 kA0 = *reinterpret_cast<const bf16x8*>(kp + offK0);
      bf16x8 kA1 = *reinterpret_cast<const bf16x8*>(kp + offK1);
      bf16x8 kB0 = *reinterpret_cast<const bf16x8*>(kp + 512 + offK0);
      bf16x8 kB1 = *reinterpret_cast<const bf16x8*>(kp + 512 + offK1);
      f32x4 bA = *reinterpret_cast<const f32x4*>(&B_[h * 32 + g * 8]);
      f32x4 bB = *reinterpret_cast<const f32x4*>(&B_[h * 32 + g * 8 + 4]);
      #pragma unroll
      for (int s = 0; s < 2; s++) {
        f32x4 sA = {}, sB = {};
        sA = __builtin_amdgcn_mfma_f32_16x16x32_bf16(kA0, qf[s][0], sA, 0, 0, 0);
        sA = __builtin_amdgcn_mfma_f32_16x16x32_bf16(kA1, qf[s][1], sA, 0, 0, 0);
        sB = __builtin_amdgcn_mfma_f32_16x16x32_bf16(kB0, qf[s][0], sB, 0, 0, 0);
        sB = __builtin_amdgcn_mfma_f32_16x16x32_bf16(kB1, qf[s][1], sB, 0, 0, 0);
        float pA[4], pB[4];
        #pragma unroll
        for (int r = 0; r < 4; r++) {
          pA[r] = exp2a(sA[r] * S2 + bA[r]);
          pB[r] = exp2a(sB[r] * S2 + bB[r]);
        }
        union { unsigned int u[4]; bf16x8 v; } pf;
        pf.u[0] = cvtpk(pA[0], pA[1]);
        pf.u[1] = cvtpk(pA[2], pA[3]);
        pf.u[2] = cvtpk(pB[0], pB[1]);
        pf.u[3] = cvtpk(pB[2], pB[3]);
        pfr[s][h] = pf.v;
      }
    }

    #pragma unroll
    for (int db = 0; db < 4; db++) {
      const char* vp = V_ + (size_t)(db * 16 + lrow) * 128;
      bf16x8 vf0 = *reinterpret_cast<const bf16x8*>(vp + offV0);
      bf16x8 vf1 = *reinterpret_cast<const bf16x8*>(vp + offV1);
      acc[0][db] = __builtin_amdgcn_mfma_f32_16x16x32_bf16(pfr[0][0], vf0, acc[0][db], 0, 0, 0);
      acc[0][db] = __builtin_amdgcn_mfma_f32_16x16x32_bf16(pfr[0][1], vf1, acc[0][db], 0, 0, 0);
      acc[1][db] = __builtin_amdgcn_mfma_f32_16x16x32_bf16(pfr[1][0], vf0, acc[1][db], 0, 0, 0);
      acc[1][db] = __builtin_amdgcn_mfma_f32_16x16x32_bf16(pfr[1][1], vf1, acc[1][db], 0, 0, 0);
    }
    accL[0] = __builtin_amdgcn_mfma_f32_16x16x32_bf16(pfr[0][0], onesU.v, accL[0], 0, 0, 0);
    accL[0] = __builtin_amdgcn_mfma_f32_16x16x32_bf16(pfr[0][1], onesU.v, accL[0], 0, 0, 0);
    accL[1] = __builtin_amdgcn_mfma_f32_16x16x32_bf16(pfr[1][0], onesU.v, accL[1], 0, 0, 0);
    accL[1] = __builtin_amdgcn_mfma_f32_16x16x32_bf16(pfr[1][1], onesU.v, accL[1], 0, 0, 0);

    fence0();   // my next stage landed; all waves' reads of cur done
  }

  #pragma unroll
  for (int s = 0; s < 2; s++) {
    #pragma unroll
    for (int db = 0; db < 4; db++)
      #pragma unroll
      for (int r = 0; r < 4; r++) {
        size_t qrow = (size_t)bh * 1024 + q0 + s * 16 + g * 4 + r;
        acc_ws[(qrow * split + sp) * 64 + db * 16 + lrow] = acc[s][db][r];
      }
    if (lrow == 0) {
      #pragma unroll
      for (int r = 0; r < 4; r++)
        l_ws[((size_t)bh * 1024 + q0 + s * 16 + g * 4 + r) * split + sp] = accL[s][r];
    }
  }
}

// ---------------- combine partials -> normalized bf16 ao [b*n][h*d] ----------------
__global__ __launch_bounds__(256) void attn_combine(const float* __restrict__ acc_ws,
                                                    const float* __restrict__ l_ws,
                                                    unsigned short* __restrict__ ao,
                                                    int split) {
  int bid = blockIdx.x;            // 512 = bh*16 + qt
  int bh = bid >> 4, qt = bid & 15;
  int b = bh >> 4, h = bh & 15;
  int t = threadIdx.x;
  int c4 = t & 15;
  int rbase = (t >> 4) * 4;

  #pragma unroll
  for (int rr = 0; rr < 4; rr++) {
    int row = rbase + rr;
    int qx = qt * 64 + row;
    f32x4 s = {};
    float ls = 0.f;
    for (int sp = 0; sp < split; sp++) {
      size_t idx = ((size_t)bh * 1024 + qx) * split + sp;
      const f32x4 a = *reinterpret_cast<const f32x4*>(&acc_ws[idx * 64 + c4 * 4]);
      s += a;
      ls += l_ws[idx];
    }
    float inv = 1.0f / ls;
    ushort4 o;
    o.x = f2bf(s[0] * inv);
    o.y = f2bf(s[1] * inv);
    o.z = f2bf(s[2] * inv);
    o.w = f2bf(s[3] * inv);
    size_t orow = (size_t)b * N_Q + qx;
    *reinterpret_cast<ushort4*>(&ao[orow * 1024 + h * 64 + c4 * 4]) = o;
  }
}

// ---------------- launcher ----------------
extern "C" void kernel_launch(void* const* d_in, const int* in_sizes, int n_in,
                              void* d_out, int out_size, void* d_ws, size_t ws_size,
                              hipStream_t stream) {
  const float* x   = (const float*)d_in[0];
  const float* ctx = (const float*)d_in[1];
  const float* imp = (const float*)d_in[2];
  const float* Wq  = (const float*)d_in[3];
  const float* Wk  = (const float*)d_in[4];
  const float* Wv  = (const float*)d_in[5];
  const float* Wo  = (const float*)d_in[6];
  const float* bo  = (const float*)d_in[7];
  float* out = (float*)d_out;

  unsigned short* xb  = (unsigned short*)d_ws;       // 2048*1024
  unsigned short* cb  = xb  + (size_t)2048 * 1024;   // 8192*1024
  unsigned short* Wqt = cb  + (size_t)8192 * 1024;   // 1024*1024
  unsigned short* Wkt = Wqt + (size_t)1024 * 1024;
  unsigned short* Wvt = Wkt + (size_t)1024 * 1024;
  unsigned short* Wot = Wvt + (size_t)1024 * 1024;
  unsigned short* qa  = Wot + (size_t)1024 * 1024;   // [bh][n][d]   2048*1024
  unsigned short* ka  = qa  + (size_t)2048 * 1024;   // [bh][m][d]   8192*1024
  unsigned short* vtb = ka  + (size_t)8192 * 1024;   // [bh][d][m]   8192*1024
  unsigned short* ao  = vtb + (size_t)8192 * 1024;   // [b*n][h*d]   2048*1024
  float* impL = (float*)(ao + (size_t)2048 * 1024);  // 2*4096 f32, bias*LOG2E
  size_t base_bytes = (size_t)((char*)(impL + 8192) - (char*)d_ws);

  size_t per_split = (size_t)32 * 1024 * 64 * 4 + (size_t)32 * 1024 * 4;
  int split = 1, lsplit = 0;
  if (ws_size >= base_bytes + 4 * per_split) { split = 4; lsplit = 2; }
  else if (ws_size >= base_bytes + 2 * per_split) { split = 2; lsplit = 1; }
  float* acc_ws = (float*)((char*)d_ws + base_bytes);
  float* l_ws   = (float*)((char*)d_ws + base_bytes + (size_t)split * 32 * 1024 * 64 * 4);

  prep<<<2048, 256, 0, stream>>>(x, ctx, imp, xb, cb, impL);
  tcvt4<<<dim3(32, 32, 4), 256, 0, stream>>>(Wq, Wk, Wv, Wo, Wqt, Wkt, Wvt, Wot);

  gemm_qkv<<<288, 512, 0, stream>>>(xb, cb, Wqt, Wkt, Wvt, qa, ka, vtb);

  attn_kernel<<<dim3(256 * split), 256, 0, stream>>>(qa, ka, vtb, impL, acc_ws, l_ws, split, lsplit);
  attn_combine<<<512, 256, 0, stream>>>(acc_ws, l_ws, ao, split);

  gemm_o<<<128, 256, 0, stream>>>(ao, Wot, out, bo);   // 1D grid (R10 fix)
}

// Round 19
// 141.663 us; speedup vs baseline: 1.1774x; 1.1774x over previous
//
#include <hip/hip_runtime.h>
#include <stdint.h>

// ImportanceGuidedCrossAttention: B=2, N=1024, M=4096, HEADS=16, DHEAD=64
// prep; tcvt4; gemm_qkv (Q + K + V^T in ONE 1152-block launch, 128^2 tiles,
// dbuf + ONE __syncthreads() fence per K-step [m97 structure — NO
// sched_barrier(0): m141 showed it costs 874->510 TF by defeating compiler
// pipelining] + slot-XOR LDS swizzle [0 conflicts, R16/17] + V decode
// m-fastest [FETCH 90->41MB, R16/17]); fused attention (LDS K/V, permuted-K
// lane-local P, ones-MFMA lsum, split-K); combine; O proj.

typedef float f32x4 __attribute__((ext_vector_type(4)));
typedef __bf16 bf16x8 __attribute__((ext_vector_type(8)));

#define SCALE 0.125f
#define LOG2E 1.4426950408889634f
#define N_Q 1024
#define M_KV 4096
#define KDIM 1024

static __device__ __forceinline__ unsigned short f2bf(float f) {
  union { float f; unsigned int u; } v; v.f = f;
  unsigned int r = v.u + 0x7fffu + ((v.u >> 16) & 1u);  // RNE
  return (unsigned short)(r >> 16);
}
static __device__ __forceinline__ unsigned int cvtpk(float lo, float hi) {
  unsigned int r;
  asm("v_cvt_pk_bf16_f32 %0, %1, %2" : "=v"(r) : "v"(lo), "v"(hi));
  return r;
}
static __device__ __forceinline__ float exp2a(float x) {
  float r;
  asm("v_exp_f32 %0, %1" : "=v"(r) : "v"(x));
  return r;
}
static __device__ __forceinline__ void gload16(const void* g, void* l) {
  __builtin_amdgcn_global_load_lds(
      (const __attribute__((address_space(1))) void*)g,
      (__attribute__((address_space(3))) void*)l, 16, 0, 0);
}
static __device__ __forceinline__ void gload4(const void* g, void* l) {
  __builtin_amdgcn_global_load_lds(
      (const __attribute__((address_space(1))) void*)g,
      (__attribute__((address_space(3))) void*)l, 4, 0, 0);
}

// ---------------- prep: cvt x, cvt ctx, scale imp — one launch ----------------
__global__ __launch_bounds__(256) void prep(const float* __restrict__ x,
                                            const float* __restrict__ ctx,
                                            const float* __restrict__ imp,
                                            unsigned short* __restrict__ xb,
                                            unsigned short* __restrict__ cb,
                                            float* __restrict__ impL) {
  const int NX = (2048 * 1024) / 4;
  const int NC = (8192 * 1024) / 4;
  const int NI = 8192 / 4;
  int i = blockIdx.x * 256 + threadIdx.x;
  int stride = gridDim.x * 256;
  for (; i < NX + NC + NI; i += stride) {
    if (i < NX) {
      float4 v = reinterpret_cast<const float4*>(x)[i];
      ushort4 o; o.x = f2bf(v.x); o.y = f2bf(v.y); o.z = f2bf(v.z); o.w = f2bf(v.w);
      reinterpret_cast<ushort4*>(xb)[i] = o;
    } else if (i < NX + NC) {
      int j = i - NX;
      float4 v = reinterpret_cast<const float4*>(ctx)[j];
      ushort4 o; o.x = f2bf(v.x); o.y = f2bf(v.y); o.z = f2bf(v.z); o.w = f2bf(v.w);
      reinterpret_cast<ushort4*>(cb)[j] = o;
    } else {
      int j = i - NX - NC;
      float4 v = reinterpret_cast<const float4*>(imp)[j];
      float4 o; o.x = v.x * LOG2E; o.y = v.y * LOG2E; o.z = v.z * LOG2E; o.w = v.w * LOG2E;
      reinterpret_cast<float4*>(impL)[j] = o;
    }
  }
}

// ---------------- fp32 [R][C] -> bf16 [C][R] transpose-convert, 4 weights ----------------
__global__ __launch_bounds__(256) void tcvt4(const float* __restrict__ w0,
                                             const float* __restrict__ w1,
                                             const float* __restrict__ w2,
                                             const float* __restrict__ w3,
                                             unsigned short* __restrict__ o0,
                                             unsigned short* __restrict__ o1,
                                             unsigned short* __restrict__ o2,
                                             unsigned short* __restrict__ o3) {
  const int R = 1024, C = 1024;
  __shared__ float tile[32][33];
  const float* in; unsigned short* out;
  switch (blockIdx.z) {
    case 0: in = w0; out = o0; break;
    case 1: in = w1; out = o1; break;
    case 2: in = w2; out = o2; break;
    default: in = w3; out = o3; break;
  }
  int bx = blockIdx.x * 32, by = blockIdx.y * 32;
  int x = threadIdx.x & 31;
  int y0 = threadIdx.x >> 5;
  #pragma unroll
  for (int yy = y0; yy < 32; yy += 8)
    tile[yy][x] = in[(size_t)(by + yy) * C + bx + x];
  __syncthreads();
  #pragma unroll
  for (int yy = y0; yy < 32; yy += 8)
    out[(size_t)(bx + yy) * R + by + x] = f2bf(tile[x][yy]);
}

// ---------------- mega projection GEMM: Q + K + V^T, 128^2 tiles ----------------
// 1152 blocks (bijective XCD swizzle):
//  swz <128  : Q  = xb[2048x1024] @ Wqt^T  -> qa   (16m x 8n, n-fastest)
//  swz <640  : K  = cb[8192x1024] @ Wkt^T  -> ka   (64m x 8n, n-fastest: A=cb panel reuse)
//  else      : Vt = Wvt[1024x1024] @ cb^T  -> vtb  (8m x 64n, m-fastest: B=cb panel reuse)
// BK=32, 4 waves (2x2), dbuf (32KB -> 5 blocks/CU), ONE __syncthreads per
// K-step issued AFTER compute (stage latency hides under MFMAs + TLP; the
// compiler is free to pipeline across the barrier — no sched_barrier pin).
__global__ __launch_bounds__(256) void gemm_qkv(const unsigned short* __restrict__ xb,
                                                const unsigned short* __restrict__ cb,
                                                const unsigned short* __restrict__ Wqt,
                                                const unsigned short* __restrict__ Wkt,
                                                const unsigned short* __restrict__ Wvt,
                                                unsigned short* __restrict__ qa,
                                                unsigned short* __restrict__ ka,
                                                unsigned short* __restrict__ vtb) {
  const int LDT = 32;
  __shared__ __align__(16) unsigned short As[2][128 * LDT];
  __shared__ __align__(16) unsigned short Bs[2][128 * LDT];

  const int nwg = gridDim.x;                     // 1152, %8==0
  const int lin = blockIdx.x;
  const int swz = (lin & 7) * (nwg >> 3) + (lin >> 3);

  int variant, m0, n0;
  if (swz < 128)      { variant = 0; m0 = (swz >> 3) * 128;        n0 = (swz & 7) * 128; }
  else if (swz < 640) { int r = swz - 128; variant = 1; m0 = (r >> 3) * 128; n0 = (r & 7) * 128; }
  else                { int r = swz - 640; variant = 2; m0 = (r & 7) * 128;  n0 = (r >> 3) * 128; }
  const unsigned short* A  = (variant == 0) ? xb  : (variant == 1) ? cb  : Wvt;
  const unsigned short* Bt = (variant == 0) ? Wqt : (variant == 1) ? Wkt : cb;

  const int t = threadIdx.x;
  const int wave = t >> 6, lane = t & 63;
  const int wr = wave >> 1, wc = wave & 1;
  const int lrow = lane & 15, g = lane >> 4;

  f32x4 acc[4][4] = {};

  const int r16 = lane >> 2;                               // staging row in 16-row chunk
  const int cs8 = (((lane & 3) ^ ((r16 >> 1) & 3)) * 8);   // pre-swizzled src col (elems)
  const int rb = wave * 32;                                // wave's 32-row chunk
  const int gsw = (g ^ ((lrow >> 1) & 3)) * 8;             // swizzled read col (elems)

  auto STAGE = [&](int bi, int k0) {
    gload16(&A[(size_t)(m0 + rb + r16) * KDIM + k0 + cs8],       &As[bi][rb * LDT]);
    gload16(&A[(size_t)(m0 + rb + 16 + r16) * KDIM + k0 + cs8],  &As[bi][(rb + 16) * LDT]);
    gload16(&Bt[(size_t)(n0 + rb + r16) * KDIM + k0 + cs8],      &Bs[bi][rb * LDT]);
    gload16(&Bt[(size_t)(n0 + rb + 16 + r16) * KDIM + k0 + cs8], &Bs[bi][(rb + 16) * LDT]);
  };
  auto COMPUTE = [&](int buf) {
    bf16x8 af[4], bfr[4];
    #pragma unroll
    for (int mi = 0; mi < 4; mi++)
      af[mi] = *reinterpret_cast<const bf16x8*>(&As[buf][(wr * 64 + mi * 16 + lrow) * LDT + gsw]);
    #pragma unroll
    for (int ni = 0; ni < 4; ni++)
      bfr[ni] = *reinterpret_cast<const bf16x8*>(&Bs[buf][(wc * 64 + ni * 16 + lrow) * LDT + gsw]);
    #pragma unroll
    for (int mi = 0; mi < 4; mi++)
      #pragma unroll
      for (int ni = 0; ni < 4; ni++)
        acc[mi][ni] = __builtin_amdgcn_mfma_f32_16x16x32_bf16(af[mi], bfr[ni], acc[mi][ni], 0, 0, 0);
  };

  STAGE(0, 0);
  __syncthreads();

  for (int k0 = 0; k0 < KDIM; k0 += 32) {
    const int buf = (k0 >> 5) & 1;
    if (k0 + 32 < KDIM) STAGE(buf ^ 1, k0 + 32);   // issue next stage before compute
    COMPUTE(buf);
    __syncthreads();   // vmcnt(0)+lgkmcnt(0)+barrier: stage landed, reads done
  }

  // epilogue: C/D layout col=lane&15, row=g*4+reg — all variants coalesced
  #pragma unroll
  for (int mi = 0; mi < 4; mi++) {
    #pragma unroll
    for (int ni = 0; ni < 4; ni++) {
      #pragma unroll
      for (int r = 0; r < 4; r++) {
        int R = m0 + wr * 64 + mi * 16 + g * 4 + r;
        int Cc = n0 + wc * 64 + ni * 16 + lrow;
        unsigned short bv = f2bf(acc[mi][ni][r]);
        if (variant == 0) {
          int h = Cc >> 6, d = Cc & 63;
          int b = R >> 10, n = R & 1023;
          qa[(((size_t)(b * 16 + h)) * 1024 + n) * 64 + d] = bv;
        } else if (variant == 1) {
          int h = Cc >> 6, d = Cc & 63;
          int b = R >> 12, m = R & 4095;
          ka[(((size_t)(b * 16 + h)) * 4096 + m) * 64 + d] = bv;
        } else {
          int h = R >> 6, d = R & 63;        // rows are the inner (h,d) index
          int b = Cc >> 12, m = Cc & 4095;   // cols are (b,m) -> contiguous m per lane
          vtb[(((size_t)(b * 16 + h)) * 64 + d) * 4096 + m] = bv;
        }
      }
    }
  }
}

// ---------------- O-proj GEMM: out[2048][1024] = ao @ Wot^T + bo (f32) ----------------
// 1D grid of 128 blocks; same m97-style fence.
__global__ __launch_bounds__(256) void gemm_o(const unsigned short* __restrict__ A,
                                              const unsigned short* __restrict__ Bt,
                                              float* __restrict__ outp,
                                              const float* __restrict__ bias) {
  const int LDT = 32;
  __shared__ __align__(16) unsigned short As[2][128 * LDT];
  __shared__ __align__(16) unsigned short Bs[2][128 * LDT];

  const int nwg = gridDim.x;                     // 128
  const int lin = blockIdx.x;
  const int swz = (lin & 7) * (nwg >> 3) + (lin >> 3);
  const int m0 = (swz >> 3) * 128;
  const int n0 = (swz & 7) * 128;

  const int t = threadIdx.x;
  const int wave = t >> 6, lane = t & 63;
  const int wr = wave >> 1, wc = wave & 1;
  const int lrow = lane & 15, g = lane >> 4;

  f32x4 acc[4][4] = {};

  const int r16 = lane >> 2;
  const int cs8 = (((lane & 3) ^ ((r16 >> 1) & 3)) * 8);
  const int rb = wave * 32;
  const int gsw = (g ^ ((lrow >> 1) & 3)) * 8;

  auto STAGE = [&](int bi, int k0) {
    gload16(&A[(size_t)(m0 + rb + r16) * KDIM + k0 + cs8],       &As[bi][rb * LDT]);
    gload16(&A[(size_t)(m0 + rb + 16 + r16) * KDIM + k0 + cs8],  &As[bi][(rb + 16) * LDT]);
    gload16(&Bt[(size_t)(n0 + rb + r16) * KDIM + k0 + cs8],      &Bs[bi][rb * LDT]);
    gload16(&Bt[(size_t)(n0 + rb + 16 + r16) * KDIM + k0 + cs8], &Bs[bi][(rb + 16) * LDT]);
  };
  auto COMPUTE = [&](int buf) {
    bf16x8 af[4], bfr[4];
    #pragma unroll
    for (int mi = 0; mi < 4; mi++)
      af[mi] = *reinterpret_cast<const bf16x8*>(&As[buf][(wr * 64 + mi * 16 + lrow) * LDT + gsw]);
    #pragma unroll
    for (int ni = 0; ni < 4; ni++)
      bfr[ni] = *reinterpret_cast<const bf16x8*>(&Bs[buf][(wc * 64 + ni * 16 + lrow) * LDT + gsw]);
    #pragma unroll
    for (int mi = 0; mi < 4; mi++)
      #pragma unroll
      for (int ni = 0; ni < 4; ni++)
        acc[mi][ni] = __builtin_amdgcn_mfma_f32_16x16x32_bf16(af[mi], bfr[ni], acc[mi][ni], 0, 0, 0);
  };

  STAGE(0, 0);
  __syncthreads();

  for (int k0 = 0; k0 < KDIM; k0 += 32) {
    const int buf = (k0 >> 5) & 1;
    if (k0 + 32 < KDIM) STAGE(buf ^ 1, k0 + 32);
    COMPUTE(buf);
    __syncthreads();
  }

  #pragma unroll
  for (int mi = 0; mi < 4; mi++)
    #pragma unroll
    for (int ni = 0; ni < 4; ni++)
      #pragma unroll
      for (int r = 0; r < 4; r++) {
        int R = m0 + wr * 64 + mi * 16 + g * 4 + r;
        int Cc = n0 + wc * 64 + ni * 16 + lrow;
        outp[(size_t)R * 1024 + Cc] = acc[mi][ni][r] + bias[Cc];
      }
}

// ---------------- fused attention: LDS K/V + permuted-K lane-local P ----------------
// Verified math (R8/R11); ONE __syncthreads per tile after compute.
__global__ __launch_bounds__(256, 4) void attn_kernel(const unsigned short* __restrict__ q,
                                                      const unsigned short* __restrict__ k,
                                                      const unsigned short* __restrict__ vt,
                                                      const float* __restrict__ impL,
                                                      float* __restrict__ acc_ws,
                                                      float* __restrict__ l_ws,
                                                      int split, int lsplit) {
  __shared__ __align__(16) unsigned short Ks[2][64 * 64];
  __shared__ __align__(16) unsigned short Vs[2][64 * 64];
  __shared__ __align__(16) float Bls[2][64];

  const int nwg = gridDim.x;                    // 256*split, %8==0
  const int lin = blockIdx.x;
  const int swz = (lin & 7) * (nwg >> 3) + (lin >> 3);
  const int sp = swz & (split - 1);
  const int tmp = swz >> lsplit;
  const int qt8 = tmp & 7;
  const int bh = tmp >> 3;                      // b*16+h
  const int t = threadIdx.x;
  const int wave = t >> 6, lane = t & 63;
  const int lrow = lane & 15, g = lane >> 4;
  const int q0 = qt8 * 128 + wave * 32;

  const unsigned short* qbase = q + ((size_t)bh * N_Q + q0) * 64;
  const char* kbase = (const char*)(k + (size_t)bh * M_KV * 64);
  const char* vbase = (const char*)(vt + (size_t)bh * 64 * M_KV);
  const float* ibase = impL + (size_t)(bh >> 4) * M_KV;

  const int rj = lane >> 3;
  const int cb = (lane & 7) * 16;
  const int cbsV  = cb ^ (rj << 4);
  const int cbsK0 = cb ^ ((rj & 3) << 4);
  const int cbsK1 = cb ^ (((rj & 3) | 4) << 4);
  const int row0 = wave * 16 + rj;
  const int row1 = row0 + 8;

  const int g2 = lrow >> 2, r4 = lrow & 3;
  const int krA = g2 * 8 + r4;
  const int vk = r4 | ((g2 & 1) << 2);
  const int offK0 = (g * 16) ^ (vk << 4);
  const int offK1 = (g * 16 + 64) ^ (vk << 4);
  const int swrV = (lrow & 7) << 4;
  const int offV0 = (g * 16) ^ swrV;
  const int offV1 = (g * 16 + 64) ^ swrV;

  bf16x8 qf[2][2];
  #pragma unroll
  for (int s = 0; s < 2; s++)
    #pragma unroll
    for (int ks = 0; ks < 2; ks++)
      qf[s][ks] = *reinterpret_cast<const bf16x8*>(&qbase[(size_t)(s * 16 + lrow) * 64 + ks * 32 + g * 8]);

  f32x4 acc[2][4] = {};
  f32x4 accL[2] = {};

  union { unsigned int u[4]; bf16x8 v; } onesU;
  onesU.u[0] = 0x3F803F80u; onesU.u[1] = 0x3F803F80u;
  onesU.u[2] = 0x3F803F80u; onesU.u[3] = 0x3F803F80u;

  const float S2 = SCALE * LOG2E;
  const int mspan = M_KV >> lsplit;
  const int mlo = sp * mspan;
  const int nt = mspan >> 6;

  auto STAGE = [&](int bi, int m0) {
    gload16(kbase + (size_t)(m0 + row0) * 128 + cbsK0, &Ks[bi][(wave * 16) * 64]);
    gload16(kbase + (size_t)(m0 + row1) * 128 + cbsK1, &Ks[bi][(wave * 16 + 8) * 64]);
    gload16(vbase + (size_t)row0 * 8192 + (size_t)m0 * 2 + cbsV, &Vs[bi][(wave * 16) * 64]);
    gload16(vbase + (size_t)row1 * 8192 + (size_t)m0 * 2 + cbsV, &Vs[bi][(wave * 16 + 8) * 64]);
    gload4((const char*)(ibase + m0) + lane * 4, &Bls[bi][0]);
  };

  STAGE(0, mlo);
  __syncthreads();

  for (int tt = 0; tt < nt; ++tt) {
    const int cur = tt & 1;
    if (tt + 1 < nt) STAGE(cur ^ 1, mlo + (tt + 1) * 64);   // async; waited at iter end

    const char* K_ = (const char*)&Ks[cur][0];
    const char* V_ = (const char*)&Vs[cur][0];
    const float* B_ = &Bls[cur][0];

    bf16x8 pfr[2][2];
    #pragma unroll
    for (int h = 0; h < 2; h++) {
      const char* kp = K_ + (size_t)(h * 32 + krA) * 128;
      bf16x8 kA0 = *reinterpret_cast<const bf16x8*>(kp + offK0);
      bf16x8 kA1 = *reinterpret_cast<const bf16x8*>(kp + offK1);
      bf16x8 kB0 = *reinterpret_cast<const bf16x8*>(kp + 512 + offK0);
      bf16x8 kB1 = *reinterpret_cast<const bf16x8*>(kp + 512 + offK1);
      f32x4 bA = *reinterpret_cast<const f32x4*>(&B_[h * 32 + g * 8]);
      f32x4 bB = *reinterpret_cast<const f32x4*>(&B_[h * 32 + g * 8 + 4]);
      #pragma unroll
      for (int s = 0; s < 2; s++) {
        f32x4 sA = {}, sB = {};
        sA = __builtin_amdgcn_mfma_f32_16x16x32_bf16(kA0, qf[s][0], sA, 0, 0, 0);
        sA = __builtin_amdgcn_mfma_f32_16x16x32_bf16(kA1, qf[s][1], sA, 0, 0, 0);
        sB = __builtin_amdgcn_mfma_f32_16x16x32_bf16(kB0, qf[s][0], sB, 0, 0, 0);
        sB = __builtin_amdgcn_mfma_f32_16x16x32_bf16(kB1, qf[s][1], sB, 0, 0, 0);
        float pA[4], pB[4];
        #pragma unroll
        for (int r = 0; r < 4; r++) {
          pA[r] = exp2a(sA[r] * S2 + bA[r]);
          pB[r] = exp2a(sB[r] * S2 + bB[r]);
        }
        union { unsigned int u[4]; bf16x8 v; } pf;
        pf.u[0] = cvtpk(pA[0], pA[1]);
        pf.u[1] = cvtpk(pA[2], pA[3]);
        pf.u[2] = cvtpk(pB[0], pB[1]);
        pf.u[3] = cvtpk(pB[2], pB[3]);
        pfr[s][h] = pf.v;
      }
    }

    #pragma unroll
    for (int db = 0; db < 4; db++) {
      const char* vp = V_ + (size_t)(db * 16 + lrow) * 128;
      bf16x8 vf0 = *reinterpret_cast<const bf16x8*>(vp + offV0);
      bf16x8 vf1 = *reinterpret_cast<const bf16x8*>(vp + offV1);
      acc[0][db] = __builtin_amdgcn_mfma_f32_16x16x32_bf16(pfr[0][0], vf0, acc[0][db], 0, 0, 0);
      acc[0][db] = __builtin_amdgcn_mfma_f32_16x16x32_bf16(pfr[0][1], vf1, acc[0][db], 0, 0, 0);
      acc[1][db] = __builtin_amdgcn_mfma_f32_16x16x32_bf16(pfr[1][0], vf0, acc[1][db], 0, 0, 0);
      acc[1][db] = __builtin_amdgcn_mfma_f32_16x16x32_bf16(pfr[1][1], vf1, acc[1][db], 0, 0, 0);
    }
    accL[0] = __builtin_amdgcn_mfma_f32_16x16x32_bf16(pfr[0][0], onesU.v, accL[0], 0, 0, 0);
    accL[0] = __builtin_amdgcn_mfma_f32_16x16x32_bf16(pfr[0][1], onesU.v, accL[0], 0, 0, 0);
    accL[1] = __builtin_amdgcn_mfma_f32_16x16x32_bf16(pfr[1][0], onesU.v, accL[1], 0, 0, 0);
    accL[1] = __builtin_amdgcn_mfma_f32_16x16x32_bf16(pfr[1][1], onesU.v, accL[1], 0, 0, 0);

    __syncthreads();   // stage landed + all waves' reads of cur done
  }

  #pragma unroll
  for (int s = 0; s < 2; s++) {
    #pragma unroll
    for (int db = 0; db < 4; db++)
      #pragma unroll
      for (int r = 0; r < 4; r++) {
        size_t qrow = (size_t)bh * 1024 + q0 + s * 16 + g * 4 + r;
        acc_ws[(qrow * split + sp) * 64 + db * 16 + lrow] = acc[s][db][r];
      }
    if (lrow == 0) {
      #pragma unroll
      for (int r = 0; r < 4; r++)
        l_ws[((size_t)bh * 1024 + q0 + s * 16 + g * 4 + r) * split + sp] = accL[s][r];
    }
  }
}

// ---------------- combine partials -> normalized bf16 ao [b*n][h*d] ----------------
__global__ __launch_bounds__(256) void attn_combine(const float* __restrict__ acc_ws,
                                                    const float* __restrict__ l_ws,
                                                    unsigned short* __restrict__ ao,
                                                    int split) {
  int bid = blockIdx.x;            // 512 = bh*16 + qt
  int bh = bid >> 4, qt = bid & 15;
  int b = bh >> 4, h = bh & 15;
  int t = threadIdx.x;
  int c4 = t & 15;
  int rbase = (t >> 4) * 4;

  #pragma unroll
  for (int rr = 0; rr < 4; rr++) {
    int row = rbase + rr;
    int qx = qt * 64 + row;
    f32x4 s = {};
    float ls = 0.f;
    for (int sp = 0; sp < split; sp++) {
      size_t idx = ((size_t)bh * 1024 + qx) * split + sp;
      const f32x4 a = *reinterpret_cast<const f32x4*>(&acc_ws[idx * 64 + c4 * 4]);
      s += a;
      ls += l_ws[idx];
    }
    float inv = 1.0f / ls;
    ushort4 o;
    o.x = f2bf(s[0] * inv);
    o.y = f2bf(s[1] * inv);
    o.z = f2bf(s[2] * inv);
    o.w = f2bf(s[3] * inv);
    size_t orow = (size_t)b * N_Q + qx;
    *reinterpret_cast<ushort4*>(&ao[orow * 1024 + h * 64 + c4 * 4]) = o;
  }
}

// ---------------- launcher ----------------
extern "C" void kernel_launch(void* const* d_in, const int* in_sizes, int n_in,
                              void* d_out, int out_size, void* d_ws, size_t ws_size,
                              hipStream_t stream) {
  const float* x   = (const float*)d_in[0];
  const float* ctx = (const float*)d_in[1];
  const float* imp = (const float*)d_in[2];
  const float* Wq  = (const float*)d_in[3];
  const float* Wk  = (const float*)d_in[4];
  const float* Wv  = (const float*)d_in[5];
  const float* Wo  = (const float*)d_in[6];
  const float* bo  = (const float*)d_in[7];
  float* out = (float*)d_out;

  unsigned short* xb  = (unsigned short*)d_ws;       // 2048*1024
  unsigned short* cb  = xb  + (size_t)2048 * 1024;   // 8192*1024
  unsigned short* Wqt = cb  + (size_t)8192 * 1024;   // 1024*1024
  unsigned short* Wkt = Wqt + (size_t)1024 * 1024;
  unsigned short* Wvt = Wkt + (size_t)1024 * 1024;
  unsigned short* Wot = Wvt + (size_t)1024 * 1024;
  unsigned short* qa  = Wot + (size_t)1024 * 1024;   // [bh][n][d]   2048*1024
  unsigned short* ka  = qa  + (size_t)2048 * 1024;   // [bh][m][d]   8192*1024
  unsigned short* vtb = ka  + (size_t)8192 * 1024;   // [bh][d][m]   8192*1024
  unsigned short* ao  = vtb + (size_t)8192 * 1024;   // [b*n][h*d]   2048*1024
  float* impL = (float*)(ao + (size_t)2048 * 1024);  // 2*4096 f32, bias*LOG2E
  size_t base_bytes = (size_t)((char*)(impL + 8192) - (char*)d_ws);

  size_t per_split = (size_t)32 * 1024 * 64 * 4 + (size_t)32 * 1024 * 4;
  int split = 1, lsplit = 0;
  if (ws_size >= base_bytes + 4 * per_split) { split = 4; lsplit = 2; }
  else if (ws_size >= base_bytes + 2 * per_split) { split = 2; lsplit = 1; }
  float* acc_ws = (float*)((char*)d_ws + base_bytes);
  float* l_ws   = (float*)((char*)d_ws + base_bytes + (size_t)split * 32 * 1024 * 64 * 4);

  prep<<<2048, 256, 0, stream>>>(x, ctx, imp, xb, cb, impL);
  tcvt4<<<dim3(32, 32, 4), 256, 0, stream>>>(Wq, Wk, Wv, Wo, Wqt, Wkt, Wvt, Wot);

  gemm_qkv<<<1152, 256, 0, stream>>>(xb, cb, Wqt, Wkt, Wvt, qa, ka, vtb);

  attn_kernel<<<dim3(256 * split), 256, 0, stream>>>(qa, ka, vtb, impL, acc_ws, l_ws, split, lsplit);
  attn_combine<<<512, 256, 0, stream>>>(acc_ws, l_ws, ao, split);

  gemm_o<<<128, 256, 0, stream>>>(ao, Wot, out, bo);   // 1D grid (R10 fix)
}